// Round 8
// baseline (1137.852 us; speedup 1.0000x reference)
//
#include <hip/hip_runtime.h>
#include <hip/hip_bf16.h>

#define B_    16
#define C_    128
#define H_    112
#define W_    112
#define OUTC_ 256
#define TWOC_ 256
#define HW_   (H_ * W_)           // 12544
#define CHW_  ((size_t)C_ * HW_)  // 1605632

typedef __hip_bfloat16 bf16;
typedef short bf16x8 __attribute__((ext_vector_type(8)));
typedef short s16x4  __attribute__((ext_vector_type(4)));
typedef float f32x4  __attribute__((ext_vector_type(4)));

__device__ __forceinline__ float b2f(bf16 v) { return __bfloat162float(v); }
__device__ __forceinline__ bf16  f2b(float v) { return __float2bfloat16(v); }

__device__ __forceinline__ float rd(const float* p) { return *p; }
__device__ __forceinline__ float rd(const bf16* p)  { return b2f(*p); }

__device__ __forceinline__ float fast_tanh(float v) {
    float e = __expf(2.f * v);
    return 1.f - 2.f / (e + 1.f);
}

// ---------------------------------------------------------------------------
// Probe: detect input dtype (flag=1 -> fp32, flag=0 -> bf16).
// ---------------------------------------------------------------------------
__global__ __launch_bounds__(256) void k_probe(const unsigned short* __restrict__ x,
                                               int* __restrict__ flag) {
    __shared__ int cnt[256];
    int tid = threadIdx.x;
    int c = 0;
#pragma unroll
    for (int i = 0; i < 8; ++i) {
        unsigned short u = x[tid * 8 + i];
        int e = (u >> 7) & 0xFF;
        if (e >= 135) c++;
    }
    cnt[tid] = c;
    __syncthreads();
    if (tid == 0) {
        int s = 0;
        for (int i = 0; i < 256; ++i) s += cnt[i];
        *flag = (s > 64) ? 1 : 0;
    }
}

// ---------------------------------------------------------------------------
// Weight prep: offset_w [256][128][3][3] -> split bf16 pair, k-major layout
//   wt[tap(kh*3+kw)][cc(0..3)][oc(0..255)][c'(0..31)], c = cc*32 + c'.
// ---------------------------------------------------------------------------
__global__ __launch_bounds__(256) void k_wprep(const void* __restrict__ ow,
                                               bf16* __restrict__ wth,
                                               bf16* __restrict__ wtl,
                                               const int* __restrict__ flag) {
    int i = blockIdx.x * 256 + threadIdx.x;   // 1152*256 = 294912 total
    if (i >= 9 * 4 * 256 * 32) return;
    int cp  = i & 31;
    int oc  = (i >> 5) & 255;
    int tcc = i >> 13;            // tap*4 + cc, 0..35
    int cc  = tcc & 3;
    int tap = tcc >> 2;
    int c   = cc * 32 + cp;
    size_t src = ((size_t)oc * C_ + c) * 9 + tap;
    float v = (*flag) ? ((const float*)ow)[src] : b2f(((const bf16*)ow)[src]);
    bf16 hb = f2b(v);
    float lo = v - b2f(hb);
    wth[i] = hb;
    wtl[i] = f2b(lo);
}

// ---------------------------------------------------------------------------
// Pointwise-weight prep: point_w [256][128] -> split bf16 pair, k-major
//   pw[cc(0..3)][oc(0..255)][c'(0..31)], c = cc*32 + c'.
// ---------------------------------------------------------------------------
__global__ __launch_bounds__(256) void k_pwprep(const void* __restrict__ pw,
                                                bf16* __restrict__ pwh,
                                                bf16* __restrict__ pwl,
                                                const int* __restrict__ flag) {
    int i = blockIdx.x * 256 + threadIdx.x;   // 128*256 = 32768 total
    if (i >= 4 * 256 * 32) return;
    int cp   = i & 31;
    int oc   = (i >> 5) & 255;
    int cc   = i >> 13;           // 0..3
    int c    = cc * 32 + cp;
    size_t src = (size_t)oc * C_ + c;
    float v = (*flag) ? ((const float*)pw)[src] : b2f(((const bf16*)pw)[src]);
    bf16 hb = f2b(v);
    float lo = v - b2f(hb);
    pwh[i] = hb;
    pwl[i] = f2b(lo);
}

// ---------------------------------------------------------------------------
// Kernel 1 (MFMA): offset = tanh(conv3x3(x, offset_w) + offset_b).
// Round-5 single-buffered structure (known-good 432 us total). Epilogue now
// writes offsets INTERLEAVED as float2: off2[b][c][hw] = {ox, oy}. Thread
// j-slots (0,1) and (2,3) are complete (2c, 2c+1) pairs since ocb % 4 == 0.
// Two-dispatch split (b0=0/8) kept purely for profiling visibility.
// ---------------------------------------------------------------------------
__global__ __launch_bounds__(256) void k_offset_mfma(
    const void* __restrict__ xsrc, const bf16* __restrict__ wth,
    const bf16* __restrict__ wtl, const void* __restrict__ ob,
    float2* __restrict__ off2, const int* __restrict__ flag, int b0)
{
    __shared__ alignas(16) short Sh[114 * 32];   // 7296 B
    __shared__ alignas(16) short Sl[114 * 32];   // 7296 B

    const int tid  = threadIdx.x;
    const int lane = tid & 63;
    const int wv   = tid >> 6;          // wave 0..3 -> oc base wv*64
    const int l15  = lane & 15;
    const int l4   = lane >> 4;         // 0..3
    const int hraw = blockIdx.x;        // 0..111
    // XCD-contiguous row bands: 112 = 8*14, bijective.
    const int h    = (hraw & 7) * 14 + (hraw >> 3);
    const int b    = blockIdx.y + b0;
    const int fullp = *flag;            // fp32 inputs -> run lo-correction passes

    const float* xf = (const float*)xsrc;
    const bf16*  xb = (const bf16*)xsrc;

    f32x4 acc[4][7];
    f32x4 zero = {0.f, 0.f, 0.f, 0.f};
#pragma unroll
    for (int m = 0; m < 4; ++m)
#pragma unroll
        for (int n = 0; n < 7; ++n) acc[m][n] = zero;

    for (int cc = 0; cc < 4; ++cc) {
        for (int kh = 0; kh < 3; ++kh) {
            const int row = h + kh - 1;
            const bool rowok = (row >= 0) && (row < H_);
            __syncthreads();
            // ---- stage row (h+kh-1), channels cc*32..+31, transposed ----
            // 912 items: item = (cq 0..7, n 0..113); c' = 4*cq + t; col = n-1.
            for (int i = tid; i < 912; i += 256) {
                int n  = i % 114;
                int cq = i / 114;
                int col = n - 1;
                bool ok = rowok && (col >= 0) && (col < W_);
                size_t base = ((size_t)(b * C_ + cc * 32 + cq * 4)) * HW_
                            + (size_t)row * W_ + col;
                short hs[4], ls[4];
#pragma unroll
                for (int t = 0; t < 4; ++t) {
                    float v = 0.f;
                    if (ok) v = fullp ? xf[base + (size_t)t * HW_]
                                      : b2f(xb[base + (size_t)t * HW_]);
                    bf16 hb = f2b(v);
                    float hv = b2f(hb);
                    bf16 lb = f2b(v - hv);
                    hs[t] = *(short*)&hb;
                    ls[t] = *(short*)&lb;
                }
                int ob_ = (cq * 8) ^ (((n >> 1) & 3) << 4);   // swizzled byte off in 64B row
                int so  = n * 32 + (ob_ >> 1);                // short index
                s16x4 th, tl;
                th[0] = hs[0]; th[1] = hs[1]; th[2] = hs[2]; th[3] = hs[3];
                tl[0] = ls[0]; tl[1] = ls[1]; tl[2] = ls[2]; tl[3] = ls[3];
                *(s16x4*)&Sh[so] = th;
                *(s16x4*)&Sl[so] = tl;
            }
            __syncthreads();

            // ---- 3 k-steps (kw taps) over the staged row ----
            for (int kw = 0; kw < 3; ++kw) {
                const size_t wchunk = ((size_t)((kh * 3 + kw) * 4 + cc)) * (256 * 32);
                bf16x8 ah[4], al[4];
#pragma unroll
                for (int m = 0; m < 4; ++m) {
                    size_t aoff = (size_t)(wv * 64 + m * 16 + l15) * 32 + 8 * l4;
                    ah[m] = *(const bf16x8*)(wth + wchunk + aoff);
                }
                if (fullp) {
#pragma unroll
                    for (int m = 0; m < 4; ++m) {
                        size_t aoff = (size_t)(wv * 64 + m * 16 + l15) * 32 + 8 * l4;
                        al[m] = *(const bf16x8*)(wtl + wchunk + aoff);
                    }
                }
#pragma unroll
                for (int n = 0; n < 7; ++n) {
                    int rowb = n * 16 + l15 + kw;                    // 0..113
                    int o2   = (16 * l4) ^ (((rowb >> 1) & 3) << 4); // swizzled byte off
                    int so   = rowb * 32 + (o2 >> 1);
                    bf16x8 xh = *(const bf16x8*)&Sh[so];
#pragma unroll
                    for (int m = 0; m < 4; ++m)
                        acc[m][n] = __builtin_amdgcn_mfma_f32_16x16x32_bf16(
                            ah[m], xh, acc[m][n], 0, 0, 0);
                    if (fullp) {
                        bf16x8 xl = *(const bf16x8*)&Sl[so];
#pragma unroll
                        for (int m = 0; m < 4; ++m)
                            acc[m][n] = __builtin_amdgcn_mfma_f32_16x16x32_bf16(
                                ah[m], xl, acc[m][n], 0, 0, 0);
#pragma unroll
                        for (int m = 0; m < 4; ++m)
                            acc[m][n] = __builtin_amdgcn_mfma_f32_16x16x32_bf16(
                                al[m], xh, acc[m][n], 0, 0, 0);
                    }
                }
            }
        }
    }

    // ---- epilogue: bias + tanh, float2-interleaved offset store ----
    // D layout: col=l15 -> w, row=l4*4+j -> oc. ocb%4==0, so j=(0,1) is the
    // (ox,oy) pair of channel c0=ocb/2 and j=(2,3) of channel c0+1.
#pragma unroll
    for (int m = 0; m < 4; ++m) {
        int ocb = wv * 64 + m * 16 + l4 * 4;
        float bias[4];
#pragma unroll
        for (int j = 0; j < 4; ++j)
            bias[j] = fullp ? ((const float*)ob)[ocb + j]
                            : b2f(((const bf16*)ob)[ocb + j]);
        int c0 = ocb >> 1;   // even
#pragma unroll
        for (int n = 0; n < 7; ++n) {
            int w = n * 16 + l15;
            float vx0 = fast_tanh(acc[m][n][0] + bias[0]);
            float vy0 = fast_tanh(acc[m][n][1] + bias[1]);
            float vx1 = fast_tanh(acc[m][n][2] + bias[2]);
            float vy1 = fast_tanh(acc[m][n][3] + bias[3]);
            size_t base = ((size_t)(b * C_) + c0) * HW_ + (size_t)h * W_ + w;
            off2[base]       = float2{vx0, vy0};
            off2[base + HW_] = float2{vx1, vy1};
        }
    }
}

// ---------------------------------------------------------------------------
// Kernel 2: depthwise 3x3. grid (49, C, B). Reads original x (templated).
// ---------------------------------------------------------------------------
template <typename TI>
__device__ void dw_body(const TI* __restrict__ x, const TI* __restrict__ dw,
                        bf16* __restrict__ out) {
    int hw = blockIdx.x * 256 + threadIdx.x;  // 49*256 == 12544
    int c = blockIdx.y, b = blockIdx.z;
    int h = hw / W_, w = hw - h * W_;
    float wv[9];
#pragma unroll
    for (int k = 0; k < 9; ++k) wv[k] = rd(dw + c * 9 + k);
    const TI* xc = x + (size_t)b * CHW_ + (size_t)c * HW_;
    float acc = 0.f;
#pragma unroll
    for (int kh = 0; kh < 3; ++kh) {
        int hh = h + kh - 1;
        bool hv = (hh >= 0) && (hh < H_);
#pragma unroll
        for (int kw = 0; kw < 3; ++kw) {
            int ww = w + kw - 1;
            bool v = hv && (ww >= 0) && (ww < W_);
            acc += (v ? rd(xc + hh * W_ + ww) : 0.f) * wv[kh * 3 + kw];
        }
    }
    out[(size_t)(b * C_ + c) * HW_ + hw] = f2b(acc);
}

__global__ __launch_bounds__(256) void k_dw(const void* x, const void* dw,
                                            bf16* out, const int* flag) {
    if (*flag) dw_body<float>((const float*)x, (const float*)dw, out);
    else       dw_body<bf16>((const bf16*)x, (const bf16*)dw, out);
}

// ---------------------------------------------------------------------------
// Kernel 3: grid sample, LONG-STREAM version. grid (C, B): each block owns
// one (b,c) channel and loops 49 x 256 pixels. Per block: one contiguous
// 100 KB float2 offset stream, gathers confined to one 25 KB dwout channel
// (L2-resident), contiguous 25 KB samp write, block-uniform gbase branch.
// Channel c uses interleaved offset pair off2[b][c]; BOTH coordinate bases
// are gX[w] for c<64 and gY[h] for c>=64 (ref reshape quirk).
// ---------------------------------------------------------------------------
__global__ __launch_bounds__(256) void k_sample(
    const float2* __restrict__ off2, const bf16* __restrict__ dwout,
    bf16* __restrict__ samp) {
    const int c = blockIdx.x, b = blockIdx.y;
    const int tid = threadIdx.x;
    const bool useX = (c < 64);

    const float2* o2 = off2 + (size_t)(b * C_ + c) * HW_;
    const bf16*   p  = dwout + (size_t)(b * C_ + c) * HW_;
    bf16*         s  = samp + (size_t)(b * C_ + c) * HW_;

#pragma unroll 1
    for (int it = 0; it < 49; ++it) {
        int hw = it * 256 + tid;
        int h = hw / W_, w = hw - h * W_;
        float2 o = o2[hw];
        float gbase = useX ? (-1.f + 2.f * (float)w / 111.f)
                           : (-1.f + 2.f * (float)h / 111.f);
        float gx = fminf(fmaxf(gbase + o.x, -1.f), 1.f);
        float gy = fminf(fmaxf(gbase + o.y, -1.f), 1.f);
        float ix = (gx + 1.f) * 56.f - 0.5f;
        float iy = (gy + 1.f) * 56.f - 0.5f;
        float x0f = floorf(ix), y0f = floorf(iy);
        float wx = ix - x0f, wy = iy - y0f;
        int x0 = (int)x0f, y0 = (int)y0f;

        float v00 = 0.f, v01 = 0.f, v10 = 0.f, v11 = 0.f;
        bool y0v = (y0 >= 0) && (y0 < H_), y1v = (y0 + 1 >= 0) && (y0 + 1 < H_);
        bool x0v = (x0 >= 0) && (x0 < W_), x1v = (x0 + 1 >= 0) && (x0 + 1 < W_);
        if (y0v && x0v) v00 = b2f(p[y0 * W_ + x0]);
        if (y0v && x1v) v01 = b2f(p[y0 * W_ + x0 + 1]);
        if (y1v && x0v) v10 = b2f(p[(y0 + 1) * W_ + x0]);
        if (y1v && x1v) v11 = b2f(p[(y0 + 1) * W_ + x0 + 1]);

        float v = v00 * (1.f - wx) * (1.f - wy) + v01 * wx * (1.f - wy)
                + v10 * (1.f - wx) * wy + v11 * wx * wy;
        s[hw] = f2b(v);
    }
}

// ---------------------------------------------------------------------------
// Kernel 4 (MFMA pointwise, LDS-staged): one block per (b, h).
// out[256 oc][112 w] = point_w[256][128] x samp[., 128 c, row h].
// Stage: 7 coalesced bf16x8 global loads/thread into SP[c][w], row stride
// 114 shorts (228 B) -> all LDS access patterns <=2-way bank aliasing (free).
// Fragments: 8 ds_read_u16 per (cc,n); k-map k=8*l4+j identical to A-pack.
// ---------------------------------------------------------------------------
__global__ __launch_bounds__(256) void k_pw_mfma(
    const bf16* __restrict__ samp, const bf16* __restrict__ pwh,
    const bf16* __restrict__ pwl, void* __restrict__ out,
    const int* __restrict__ flag)
{
    __shared__ short SP[C_ * 114];   // 29184 B

    const int tid  = threadIdx.x;
    const int lane = tid & 63;
    const int wv   = tid >> 6;
    const int l15  = lane & 15;
    const int l4   = lane >> 4;
    const int hraw = blockIdx.x;
    const int h    = (hraw & 7) * 14 + (hraw >> 3);
    const int b    = blockIdx.y;
    const int fullp = *flag;

    const bf16* srow = samp + (size_t)b * C_ * HW_ + (size_t)h * W_;

    // ---- stage row slice [128 c][112 w] into LDS ----
#pragma unroll
    for (int it = 0; it < 7; ++it) {
        int i  = it * 256 + tid;      // 0..1791 = 128 c * 14 wchunks
        int c  = i / 14;
        int wc = i - c * 14;
        bf16x8 v = *(const bf16x8*)(srow + (size_t)c * HW_ + wc * 8);
        short* d = &SP[c * 114 + wc * 8];
#pragma unroll
        for (int t = 0; t < 8; ++t) d[t] = v[t];
    }
    __syncthreads();

    f32x4 acc[4][7];
    f32x4 zero = {0.f, 0.f, 0.f, 0.f};
#pragma unroll
    for (int m = 0; m < 4; ++m)
#pragma unroll
        for (int n = 0; n < 7; ++n) acc[m][n] = zero;

    for (int cc = 0; cc < 4; ++cc) {
        bf16x8 ah[4], al[4];
#pragma unroll
        for (int m = 0; m < 4; ++m) {
            size_t aoff = ((size_t)cc * 256 + (wv * 64 + m * 16 + l15)) * 32 + 8 * l4;
            ah[m] = *(const bf16x8*)(pwh + aoff);
        }
        if (fullp) {
#pragma unroll
            for (int m = 0; m < 4; ++m) {
                size_t aoff = ((size_t)cc * 256 + (wv * 64 + m * 16 + l15)) * 32 + 8 * l4;
                al[m] = *(const bf16x8*)(pwl + aoff);
            }
        }
        const int c0 = cc * 32 + 8 * l4;
#pragma unroll
        for (int n = 0; n < 7; ++n) {
            int w = n * 16 + l15;
            bf16x8 xv;
#pragma unroll
            for (int j = 0; j < 8; ++j) xv[j] = SP[(c0 + j) * 114 + w];
#pragma unroll
            for (int m = 0; m < 4; ++m)
                acc[m][n] = __builtin_amdgcn_mfma_f32_16x16x32_bf16(
                    ah[m], xv, acc[m][n], 0, 0, 0);
            if (fullp) {
#pragma unroll
                for (int m = 0; m < 4; ++m)
                    acc[m][n] = __builtin_amdgcn_mfma_f32_16x16x32_bf16(
                        al[m], xv, acc[m][n], 0, 0, 0);
            }
        }
    }

    // ---- epilogue: D layout col=l15 -> w, row=l4*4+j -> oc ----
#pragma unroll
    for (int m = 0; m < 4; ++m) {
        int ocb = wv * 64 + m * 16 + l4 * 4;
#pragma unroll
        for (int n = 0; n < 7; ++n) {
            int w = n * 16 + l15;
#pragma unroll
            for (int j = 0; j < 4; ++j) {
                size_t o = ((size_t)(b * OUTC_ + ocb + j)) * HW_ + (size_t)h * W_ + w;
                if (fullp) ((float*)out)[o] = acc[m][n][j];
                else       ((bf16*)out)[o]  = f2b(acc[m][n][j]);
            }
        }
    }
}

// ---------------------------------------------------------------------------
// Workspace layout (~309.6 MB):
//   [0,256)                       : dtype flag
//   [256, +205520896)             : off2 float2 (B*C*HW pairs)
//   then wth bf16 (589824 B), wtl bf16 (589824 B),
//        pwh bf16 (65536 B),  pwl bf16 (65536 B)
//   then dwout bf16 (51380224 B), samp bf16 (51380224 B)
// ---------------------------------------------------------------------------
extern "C" void kernel_launch(void* const* d_in, const int* in_sizes, int n_in,
                              void* d_out, int out_size, void* d_ws, size_t ws_size,
                              hipStream_t stream) {
    (void)in_sizes; (void)n_in; (void)out_size; (void)ws_size;
    const void* x        = d_in[0];
    const void* depth_w  = d_in[1];
    const void* point_w  = d_in[2];
    const void* offset_w = d_in[3];
    const void* offset_b = d_in[4];

    char* ws = (char*)d_ws;
    int*   flag = (int*)ws;
    const size_t off_bytes = (size_t)B_ * C_ * HW_ * 8;    // 205,520,896
    float2* off2 = (float2*)(ws + 256);
    bf16*  wth  = (bf16*)(ws + 256 + off_bytes);
    bf16*  wtl  = wth + 9 * 4 * 256 * 32;                  // +294912 elems
    bf16*  pwh  = wtl + 9 * 4 * 256 * 32;                  // +294912 elems
    bf16*  pwl  = pwh + 4 * 256 * 32;                      // +32768 elems
    bf16* dwout = pwl + 4 * 256 * 32;                      // +32768 elems
    bf16* samp  = dwout + (size_t)B_ * C_ * HW_;           // +25690112 elems

    k_probe      <<<1, 256, 0, stream>>>((const unsigned short*)x, flag);
    k_wprep      <<<1152, 256, 0, stream>>>(offset_w, wth, wtl, flag);
    k_pwprep     <<<128, 256, 0, stream>>>(point_w, pwh, pwl, flag);
    // Two half-batch dispatches (profiling visibility; 896 blocks = 3.5/CU).
    k_offset_mfma<<<dim3(H_, 8), 256, 0, stream>>>(x, wth, wtl, offset_b, off2, flag, 0);
    k_offset_mfma<<<dim3(H_, 8), 256, 0, stream>>>(x, wth, wtl, offset_b, off2, flag, 8);
    k_dw         <<<dim3(49, C_, B_), 256, 0, stream>>>(x, depth_w, dwout, flag);
    k_sample     <<<dim3(C_, B_), 256, 0, stream>>>(off2, dwout, samp);
    k_pw_mfma    <<<dim3(H_, B_), 256, 0, stream>>>(samp, pwh, pwl, d_out, flag);
}

// Round 9
// 966.093 us; speedup vs baseline: 1.1778x; 1.1778x over previous
//
#include <hip/hip_runtime.h>
#include <hip/hip_bf16.h>

#define B_    16
#define C_    128
#define H_    112
#define W_    112
#define OUTC_ 256
#define TWOC_ 256
#define HW_   (H_ * W_)           // 12544
#define CHW_  ((size_t)C_ * HW_)  // 1605632

typedef __hip_bfloat16 bf16;
typedef short bf16x8 __attribute__((ext_vector_type(8)));
typedef short s16x4  __attribute__((ext_vector_type(4)));
typedef float f32x4  __attribute__((ext_vector_type(4)));

__device__ __forceinline__ float b2f(bf16 v) { return __bfloat162float(v); }
__device__ __forceinline__ bf16  f2b(float v) { return __float2bfloat16(v); }

__device__ __forceinline__ float rd(const float* p) { return *p; }
__device__ __forceinline__ float rd(const bf16* p)  { return b2f(*p); }

__device__ __forceinline__ float fast_tanh(float v) {
    float e = __expf(2.f * v);
    return 1.f - 2.f / (e + 1.f);
}

// ---------------------------------------------------------------------------
// Probe: detect input dtype (flag=1 -> fp32, flag=0 -> bf16).
// ---------------------------------------------------------------------------
__global__ __launch_bounds__(256) void k_probe(const unsigned short* __restrict__ x,
                                               int* __restrict__ flag) {
    __shared__ int cnt[256];
    int tid = threadIdx.x;
    int c = 0;
#pragma unroll
    for (int i = 0; i < 8; ++i) {
        unsigned short u = x[tid * 8 + i];
        int e = (u >> 7) & 0xFF;
        if (e >= 135) c++;
    }
    cnt[tid] = c;
    __syncthreads();
    if (tid == 0) {
        int s = 0;
        for (int i = 0; i < 256; ++i) s += cnt[i];
        *flag = (s > 64) ? 1 : 0;
    }
}

// ---------------------------------------------------------------------------
// Weight prep: offset_w [256][128][3][3] -> split bf16 pair, k-major layout
//   wt[tap(kh*3+kw)][cc(0..3)][oc(0..255)][c'(0..31)], c = cc*32 + c'.
// ---------------------------------------------------------------------------
__global__ __launch_bounds__(256) void k_wprep(const void* __restrict__ ow,
                                               bf16* __restrict__ wth,
                                               bf16* __restrict__ wtl,
                                               const int* __restrict__ flag) {
    int i = blockIdx.x * 256 + threadIdx.x;   // 1152*256 = 294912 total
    if (i >= 9 * 4 * 256 * 32) return;
    int cp  = i & 31;
    int oc  = (i >> 5) & 255;
    int tcc = i >> 13;            // tap*4 + cc, 0..35
    int cc  = tcc & 3;
    int tap = tcc >> 2;
    int c   = cc * 32 + cp;
    size_t src = ((size_t)oc * C_ + c) * 9 + tap;
    float v = (*flag) ? ((const float*)ow)[src] : b2f(((const bf16*)ow)[src]);
    bf16 hb = f2b(v);
    float lo = v - b2f(hb);
    wth[i] = hb;
    wtl[i] = f2b(lo);
}

// ---------------------------------------------------------------------------
// Pointwise-weight prep: point_w [256][128] -> split bf16 pair, k-major
//   pw[cc(0..3)][oc(0..255)][c'(0..31)], c = cc*32 + c'.
// ---------------------------------------------------------------------------
__global__ __launch_bounds__(256) void k_pwprep(const void* __restrict__ pw,
                                                bf16* __restrict__ pwh,
                                                bf16* __restrict__ pwl,
                                                const int* __restrict__ flag) {
    int i = blockIdx.x * 256 + threadIdx.x;   // 128*256 = 32768 total
    if (i >= 4 * 256 * 32) return;
    int cp   = i & 31;
    int oc   = (i >> 5) & 255;
    int cc   = i >> 13;           // 0..3
    int c    = cc * 32 + cp;
    size_t src = (size_t)oc * C_ + c;
    float v = (*flag) ? ((const float*)pw)[src] : b2f(((const bf16*)pw)[src]);
    bf16 hb = f2b(v);
    float lo = v - b2f(hb);
    pwh[i] = hb;
    pwl[i] = f2b(lo);
}

// ---------------------------------------------------------------------------
// Kernel 1 (MFMA): offset = tanh(conv3x3(x, offset_w) + offset_b).
// Round-5 single-buffered structure (known-good). Epilogue writes offsets
// INTERLEAVED as float2: off2[b][c][hw] = {ox, oy} (round-8, verified).
// Two-dispatch split (b0=0/8) kept purely for profiling visibility.
// ---------------------------------------------------------------------------
__global__ __launch_bounds__(256) void k_offset_mfma(
    const void* __restrict__ xsrc, const bf16* __restrict__ wth,
    const bf16* __restrict__ wtl, const void* __restrict__ ob,
    float2* __restrict__ off2, const int* __restrict__ flag, int b0)
{
    __shared__ alignas(16) short Sh[114 * 32];   // 7296 B
    __shared__ alignas(16) short Sl[114 * 32];   // 7296 B

    const int tid  = threadIdx.x;
    const int lane = tid & 63;
    const int wv   = tid >> 6;          // wave 0..3 -> oc base wv*64
    const int l15  = lane & 15;
    const int l4   = lane >> 4;         // 0..3
    const int hraw = blockIdx.x;        // 0..111
    // XCD-contiguous row bands: 112 = 8*14, bijective.
    const int h    = (hraw & 7) * 14 + (hraw >> 3);
    const int b    = blockIdx.y + b0;
    const int fullp = *flag;            // fp32 inputs -> run lo-correction passes

    const float* xf = (const float*)xsrc;
    const bf16*  xb = (const bf16*)xsrc;

    f32x4 acc[4][7];
    f32x4 zero = {0.f, 0.f, 0.f, 0.f};
#pragma unroll
    for (int m = 0; m < 4; ++m)
#pragma unroll
        for (int n = 0; n < 7; ++n) acc[m][n] = zero;

    for (int cc = 0; cc < 4; ++cc) {
        for (int kh = 0; kh < 3; ++kh) {
            const int row = h + kh - 1;
            const bool rowok = (row >= 0) && (row < H_);
            __syncthreads();
            // ---- stage row (h+kh-1), channels cc*32..+31, transposed ----
            // 912 items: item = (cq 0..7, n 0..113); c' = 4*cq + t; col = n-1.
            for (int i = tid; i < 912; i += 256) {
                int n  = i % 114;
                int cq = i / 114;
                int col = n - 1;
                bool ok = rowok && (col >= 0) && (col < W_);
                size_t base = ((size_t)(b * C_ + cc * 32 + cq * 4)) * HW_
                            + (size_t)row * W_ + col;
                short hs[4], ls[4];
#pragma unroll
                for (int t = 0; t < 4; ++t) {
                    float v = 0.f;
                    if (ok) v = fullp ? xf[base + (size_t)t * HW_]
                                      : b2f(xb[base + (size_t)t * HW_]);
                    bf16 hb = f2b(v);
                    float hv = b2f(hb);
                    bf16 lb = f2b(v - hv);
                    hs[t] = *(short*)&hb;
                    ls[t] = *(short*)&lb;
                }
                int ob_ = (cq * 8) ^ (((n >> 1) & 3) << 4);   // swizzled byte off in 64B row
                int so  = n * 32 + (ob_ >> 1);                // short index
                s16x4 th, tl;
                th[0] = hs[0]; th[1] = hs[1]; th[2] = hs[2]; th[3] = hs[3];
                tl[0] = ls[0]; tl[1] = ls[1]; tl[2] = ls[2]; tl[3] = ls[3];
                *(s16x4*)&Sh[so] = th;
                *(s16x4*)&Sl[so] = tl;
            }
            __syncthreads();

            // ---- 3 k-steps (kw taps) over the staged row ----
            for (int kw = 0; kw < 3; ++kw) {
                const size_t wchunk = ((size_t)((kh * 3 + kw) * 4 + cc)) * (256 * 32);
                bf16x8 ah[4], al[4];
#pragma unroll
                for (int m = 0; m < 4; ++m) {
                    size_t aoff = (size_t)(wv * 64 + m * 16 + l15) * 32 + 8 * l4;
                    ah[m] = *(const bf16x8*)(wth + wchunk + aoff);
                }
                if (fullp) {
#pragma unroll
                    for (int m = 0; m < 4; ++m) {
                        size_t aoff = (size_t)(wv * 64 + m * 16 + l15) * 32 + 8 * l4;
                        al[m] = *(const bf16x8*)(wtl + wchunk + aoff);
                    }
                }
#pragma unroll
                for (int n = 0; n < 7; ++n) {
                    int rowb = n * 16 + l15 + kw;                    // 0..113
                    int o2   = (16 * l4) ^ (((rowb >> 1) & 3) << 4); // swizzled byte off
                    int so   = rowb * 32 + (o2 >> 1);
                    bf16x8 xh = *(const bf16x8*)&Sh[so];
#pragma unroll
                    for (int m = 0; m < 4; ++m)
                        acc[m][n] = __builtin_amdgcn_mfma_f32_16x16x32_bf16(
                            ah[m], xh, acc[m][n], 0, 0, 0);
                    if (fullp) {
                        bf16x8 xl = *(const bf16x8*)&Sl[so];
#pragma unroll
                        for (int m = 0; m < 4; ++m)
                            acc[m][n] = __builtin_amdgcn_mfma_f32_16x16x32_bf16(
                                ah[m], xl, acc[m][n], 0, 0, 0);
#pragma unroll
                        for (int m = 0; m < 4; ++m)
                            acc[m][n] = __builtin_amdgcn_mfma_f32_16x16x32_bf16(
                                al[m], xh, acc[m][n], 0, 0, 0);
                    }
                }
            }
        }
    }

    // ---- epilogue: bias + tanh, float2-interleaved offset store ----
    // D layout: col=l15 -> w, row=l4*4+j -> oc. ocb%4==0, so j=(0,1) is the
    // (ox,oy) pair of channel c0=ocb/2 and j=(2,3) of channel c0+1.
#pragma unroll
    for (int m = 0; m < 4; ++m) {
        int ocb = wv * 64 + m * 16 + l4 * 4;
        float bias[4];
#pragma unroll
        for (int j = 0; j < 4; ++j)
            bias[j] = fullp ? ((const float*)ob)[ocb + j]
                            : b2f(((const bf16*)ob)[ocb + j]);
        int c0 = ocb >> 1;   // even
#pragma unroll
        for (int n = 0; n < 7; ++n) {
            int w = n * 16 + l15;
            float vx0 = fast_tanh(acc[m][n][0] + bias[0]);
            float vy0 = fast_tanh(acc[m][n][1] + bias[1]);
            float vx1 = fast_tanh(acc[m][n][2] + bias[2]);
            float vy1 = fast_tanh(acc[m][n][3] + bias[3]);
            size_t base = ((size_t)(b * C_) + c0) * HW_ + (size_t)h * W_ + w;
            off2[base]       = float2{vx0, vy0};
            off2[base + HW_] = float2{vx1, vy1};
        }
    }
}

// ---------------------------------------------------------------------------
// Kernel 2: depthwise 3x3. grid (49, C, B). Reads original x (templated).
// ---------------------------------------------------------------------------
template <typename TI>
__device__ void dw_body(const TI* __restrict__ x, const TI* __restrict__ dw,
                        bf16* __restrict__ out) {
    int hw = blockIdx.x * 256 + threadIdx.x;  // 49*256 == 12544
    int c = blockIdx.y, b = blockIdx.z;
    int h = hw / W_, w = hw - h * W_;
    float wv[9];
#pragma unroll
    for (int k = 0; k < 9; ++k) wv[k] = rd(dw + c * 9 + k);
    const TI* xc = x + (size_t)b * CHW_ + (size_t)c * HW_;
    float acc = 0.f;
#pragma unroll
    for (int kh = 0; kh < 3; ++kh) {
        int hh = h + kh - 1;
        bool hv = (hh >= 0) && (hh < H_);
#pragma unroll
        for (int kw = 0; kw < 3; ++kw) {
            int ww = w + kw - 1;
            bool v = hv && (ww >= 0) && (ww < W_);
            acc += (v ? rd(xc + hh * W_ + ww) : 0.f) * wv[kh * 3 + kw];
        }
    }
    out[(size_t)(b * C_ + c) * HW_ + hw] = f2b(acc);
}

__global__ __launch_bounds__(256) void k_dw(const void* x, const void* dw,
                                            bf16* out, const int* flag) {
    if (*flag) dw_body<float>((const float*)x, (const float*)dw, out);
    else       dw_body<bf16>((const bf16*)x, (const bf16*)dw, out);
}

// ---------------------------------------------------------------------------
// Kernel 3: grid sample, VMEM-minimized. Round-2 grid structure (49, C, B) —
// the locality/MLP shape that measured 296 us — with ops/pixel cut 7 -> 4:
//   1 float2 off2 load, 2 pair-loads (v00|v01 and v10|v11 are w-adjacent
//   bf16 -> one 4B load each, bf16->f32 via shift/mask, bit-identical),
//   1 store. Interior fast path (x0,y0 in [0,110], ~96.5% of pixels);
//   edge pixels use the old 4 guarded scalar gathers.
// Channel c uses offset pair off2[b][c]; BOTH coordinate bases are gX[w]
// for c<64 and gY[h] for c>=64 (ref reshape quirk).
// ---------------------------------------------------------------------------
__global__ __launch_bounds__(256) void k_sample(
    const float2* __restrict__ off2, const bf16* __restrict__ dwout,
    bf16* __restrict__ samp) {
    int hw = blockIdx.x * 256 + threadIdx.x;
    int c = blockIdx.y, b = blockIdx.z;
    int h = hw / W_, w = hw - h * W_;

    float2 o = off2[(size_t)(b * C_ + c) * HW_ + hw];
    float gbase = (c < 64) ? (-1.f + 2.f * (float)w / 111.f)
                           : (-1.f + 2.f * (float)h / 111.f);
    float gx = fminf(fmaxf(gbase + o.x, -1.f), 1.f);
    float gy = fminf(fmaxf(gbase + o.y, -1.f), 1.f);
    float ix = (gx + 1.f) * 56.f - 0.5f;
    float iy = (gy + 1.f) * 56.f - 0.5f;
    float x0f = floorf(ix), y0f = floorf(iy);
    float wx = ix - x0f, wy = iy - y0f;
    int x0 = (int)x0f, y0 = (int)y0f;

    const bf16* p = dwout + (size_t)(b * C_ + c) * HW_;
    float v00, v01, v10, v11;
    if (x0 >= 0 && x0 <= (W_ - 2) && y0 >= 0 && y0 <= (H_ - 2)) {
        // interior: two 4B pair loads (2B-aligned)
        unsigned u0, u1;
        __builtin_memcpy(&u0, p + y0 * W_ + x0, 4);
        __builtin_memcpy(&u1, p + (y0 + 1) * W_ + x0, 4);
        v00 = __uint_as_float(u0 << 16);
        v01 = __uint_as_float(u0 & 0xFFFF0000u);
        v10 = __uint_as_float(u1 << 16);
        v11 = __uint_as_float(u1 & 0xFFFF0000u);
    } else {
        v00 = v01 = v10 = v11 = 0.f;
        bool y0v = (y0 >= 0) && (y0 < H_), y1v = (y0 + 1 >= 0) && (y0 + 1 < H_);
        bool x0v = (x0 >= 0) && (x0 < W_), x1v = (x0 + 1 >= 0) && (x0 + 1 < W_);
        if (y0v && x0v) v00 = b2f(p[y0 * W_ + x0]);
        if (y0v && x1v) v01 = b2f(p[y0 * W_ + x0 + 1]);
        if (y1v && x0v) v10 = b2f(p[(y0 + 1) * W_ + x0]);
        if (y1v && x1v) v11 = b2f(p[(y0 + 1) * W_ + x0 + 1]);
    }

    float v = v00 * (1.f - wx) * (1.f - wy) + v01 * wx * (1.f - wy)
            + v10 * (1.f - wx) * wy + v11 * wx * wy;
    samp[(size_t)(b * C_ + c) * HW_ + hw] = f2b(v);
}

// ---------------------------------------------------------------------------
// Kernel 4 (MFMA pointwise, LDS-staged): one block per (b, h).
// out[256 oc][112 w] = point_w[256][128] x samp[., 128 c, row h].
// Stage: 7 coalesced bf16x8 global loads/thread into SP[c][w], row stride
// 114 shorts (228 B) -> all LDS access patterns <=2-way bank aliasing (free).
// Fragments: 8 ds_read_u16 per (cc,n); k-map k=8*l4+j identical to A-pack.
// ---------------------------------------------------------------------------
__global__ __launch_bounds__(256) void k_pw_mfma(
    const bf16* __restrict__ samp, const bf16* __restrict__ pwh,
    const bf16* __restrict__ pwl, void* __restrict__ out,
    const int* __restrict__ flag)
{
    __shared__ short SP[C_ * 114];   // 29184 B

    const int tid  = threadIdx.x;
    const int lane = tid & 63;
    const int wv   = tid >> 6;
    const int l15  = lane & 15;
    const int l4   = lane >> 4;
    const int hraw = blockIdx.x;
    const int h    = (hraw & 7) * 14 + (hraw >> 3);
    const int b    = blockIdx.y;
    const int fullp = *flag;

    const bf16* srow = samp + (size_t)b * C_ * HW_ + (size_t)h * W_;

    // ---- stage row slice [128 c][112 w] into LDS ----
#pragma unroll
    for (int it = 0; it < 7; ++it) {
        int i  = it * 256 + tid;      // 0..1791 = 128 c * 14 wchunks
        int c  = i / 14;
        int wc = i - c * 14;
        bf16x8 v = *(const bf16x8*)(srow + (size_t)c * HW_ + wc * 8);
        short* d = &SP[c * 114 + wc * 8];
#pragma unroll
        for (int t = 0; t < 8; ++t) d[t] = v[t];
    }
    __syncthreads();

    f32x4 acc[4][7];
    f32x4 zero = {0.f, 0.f, 0.f, 0.f};
#pragma unroll
    for (int m = 0; m < 4; ++m)
#pragma unroll
        for (int n = 0; n < 7; ++n) acc[m][n] = zero;

    for (int cc = 0; cc < 4; ++cc) {
        bf16x8 ah[4], al[4];
#pragma unroll
        for (int m = 0; m < 4; ++m) {
            size_t aoff = ((size_t)cc * 256 + (wv * 64 + m * 16 + l15)) * 32 + 8 * l4;
            ah[m] = *(const bf16x8*)(pwh + aoff);
        }
        if (fullp) {
#pragma unroll
            for (int m = 0; m < 4; ++m) {
                size_t aoff = ((size_t)cc * 256 + (wv * 64 + m * 16 + l15)) * 32 + 8 * l4;
                al[m] = *(const bf16x8*)(pwl + aoff);
            }
        }
        const int c0 = cc * 32 + 8 * l4;
#pragma unroll
        for (int n = 0; n < 7; ++n) {
            int w = n * 16 + l15;
            bf16x8 xv;
#pragma unroll
            for (int j = 0; j < 8; ++j) xv[j] = SP[(c0 + j) * 114 + w];
#pragma unroll
            for (int m = 0; m < 4; ++m)
                acc[m][n] = __builtin_amdgcn_mfma_f32_16x16x32_bf16(
                    ah[m], xv, acc[m][n], 0, 0, 0);
            if (fullp) {
#pragma unroll
                for (int m = 0; m < 4; ++m)
                    acc[m][n] = __builtin_amdgcn_mfma_f32_16x16x32_bf16(
                        al[m], xv, acc[m][n], 0, 0, 0);
            }
        }
    }

    // ---- epilogue: D layout col=l15 -> w, row=l4*4+j -> oc ----
#pragma unroll
    for (int m = 0; m < 4; ++m) {
        int ocb = wv * 64 + m * 16 + l4 * 4;
#pragma unroll
        for (int n = 0; n < 7; ++n) {
            int w = n * 16 + l15;
#pragma unroll
            for (int j = 0; j < 4; ++j) {
                size_t o = ((size_t)(b * OUTC_ + ocb + j)) * HW_ + (size_t)h * W_ + w;
                if (fullp) ((float*)out)[o] = acc[m][n][j];
                else       ((bf16*)out)[o]  = f2b(acc[m][n][j]);
            }
        }
    }
}

// ---------------------------------------------------------------------------
// Workspace layout (~309.6 MB):
//   [0,256)                       : dtype flag
//   [256, +205520896)             : off2 float2 (B*C*HW pairs)
//   then wth bf16 (589824 B), wtl bf16 (589824 B),
//        pwh bf16 (65536 B),  pwl bf16 (65536 B)
//   then dwout bf16 (51380224 B), samp bf16 (51380224 B)
// ---------------------------------------------------------------------------
extern "C" void kernel_launch(void* const* d_in, const int* in_sizes, int n_in,
                              void* d_out, int out_size, void* d_ws, size_t ws_size,
                              hipStream_t stream) {
    (void)in_sizes; (void)n_in; (void)out_size; (void)ws_size;
    const void* x        = d_in[0];
    const void* depth_w  = d_in[1];
    const void* point_w  = d_in[2];
    const void* offset_w = d_in[3];
    const void* offset_b = d_in[4];

    char* ws = (char*)d_ws;
    int*   flag = (int*)ws;
    const size_t off_bytes = (size_t)B_ * C_ * HW_ * 8;    // 205,520,896
    float2* off2 = (float2*)(ws + 256);
    bf16*  wth  = (bf16*)(ws + 256 + off_bytes);
    bf16*  wtl  = wth + 9 * 4 * 256 * 32;                  // +294912 elems
    bf16*  pwh  = wtl + 9 * 4 * 256 * 32;                  // +294912 elems
    bf16*  pwl  = pwh + 4 * 256 * 32;                      // +32768 elems
    bf16* dwout = pwl + 4 * 256 * 32;                      // +32768 elems
    bf16* samp  = dwout + (size_t)B_ * C_ * HW_;           // +25690112 elems

    k_probe      <<<1, 256, 0, stream>>>((const unsigned short*)x, flag);
    k_wprep      <<<1152, 256, 0, stream>>>(offset_w, wth, wtl, flag);
    k_pwprep     <<<128, 256, 0, stream>>>(point_w, pwh, pwl, flag);
    // Two half-batch dispatches (profiling visibility; 896 blocks = 3.5/CU).
    k_offset_mfma<<<dim3(H_, 8), 256, 0, stream>>>(x, wth, wtl, offset_b, off2, flag, 0);
    k_offset_mfma<<<dim3(H_, 8), 256, 0, stream>>>(x, wth, wtl, offset_b, off2, flag, 8);
    k_dw         <<<dim3(49, C_, B_), 256, 0, stream>>>(x, depth_w, dwout, flag);
    k_sample     <<<dim3(49, C_, B_), 256, 0, stream>>>(off2, dwout, samp);
    k_pw_mfma    <<<dim3(H_, B_), 256, 0, stream>>>(samp, pwh, pwl, d_out, flag);
}